// Round 9
// baseline (496.393 us; speedup 1.0000x reference)
//
#include <hip/hip_runtime.h>
#include <stdint.h>

// Problem shape (fixed by the reference): M = B*S = 8192, K = DIN = 4096, N = DOUT = 4096
#define MDIM 8192
#define KDIM 4096
#define NDIM 4096
#define BK   64
#define NKT  (KDIM / BK)   // 64 K-tiles

typedef float f32x4 __attribute__((ext_vector_type(4)));
typedef float f32x16 __attribute__((ext_vector_type(16)));
typedef _Float16 h16x8 __attribute__((ext_vector_type(8)));
typedef float fl4 __attribute__((ext_vector_type(4)));
typedef int i32x4 __attribute__((ext_vector_type(4)));

// async global->LDS, 16B per lane; LDS dest is wave-uniform base + lane*16 (HW semantics)
__device__ __forceinline__ void gload_lds16(const void* g, void* l) {
    __builtin_amdgcn_global_load_lds(
        (__attribute__((address_space(1))) void*)(uintptr_t)g,
        (__attribute__((address_space(3))) void*)(uintptr_t)l,
        16, 0, 0);
}

// ---------------- fused quant: one dispatch, both tensors ----------------
// blocks [0,2048): x fp32 -> xq fp16 (rint(x/is); integer-valued |v|<~350: fp16-exact)
// blocks [2048,3072): w int32 -> wq fp16 (|w|<=127: exact)
__global__ void __launch_bounds__(256) quant_kernel(const float* __restrict__ x,
                                                    short* __restrict__ xq,
                                                    const int* __restrict__ w,
                                                    short* __restrict__ wq,
                                                    const float* __restrict__ p_is) {
    if (blockIdx.x < 2048) {
        const float inv_is = 1.0f / p_is[0];
        const int64_t stride = (int64_t)2048 * 256 * 8;
        for (int64_t i = ((int64_t)blockIdx.x * 256 + threadIdx.x) * 8;
             i < (int64_t)MDIM * KDIM; i += stride) {
            fl4 a = __builtin_nontemporal_load((const fl4*)(x + i));
            fl4 b = __builtin_nontemporal_load((const fl4*)(x + i + 4));
            h16x8 o;
            o[0] = (_Float16)rintf(a[0] * inv_is);
            o[1] = (_Float16)rintf(a[1] * inv_is);
            o[2] = (_Float16)rintf(a[2] * inv_is);
            o[3] = (_Float16)rintf(a[3] * inv_is);
            o[4] = (_Float16)rintf(b[0] * inv_is);
            o[5] = (_Float16)rintf(b[1] * inv_is);
            o[6] = (_Float16)rintf(b[2] * inv_is);
            o[7] = (_Float16)rintf(b[3] * inv_is);
            *(h16x8*)(xq + i) = o;   // normal store: gemm re-reads xq
        }
    } else {
        const int64_t stride = (int64_t)1024 * 256 * 8;
        for (int64_t i = (((int64_t)blockIdx.x - 2048) * 256 + threadIdx.x) * 8;
             i < (int64_t)NDIM * KDIM; i += stride) {
            i32x4 a = *(const i32x4*)(w + i);
            i32x4 b = *(const i32x4*)(w + i + 4);
            h16x8 o;
            o[0] = (_Float16)(float)a[0];
            o[1] = (_Float16)(float)a[1];
            o[2] = (_Float16)(float)a[2];
            o[3] = (_Float16)(float)a[3];
            o[4] = (_Float16)(float)b[0];
            o[5] = (_Float16)(float)b[1];
            o[6] = (_Float16)(float)b[2];
            o[7] = (_Float16)(float)b[3];
            *(h16x8*)(wq + i) = o;
        }
    }
}

// -------- GEMM: 256x256, BK=64, 8 waves 2Mx4N, 8-phase (R6 map), 32x32x16 MFMA --------
// R12: keep R6's verified stage map / vmcnt(6) / PH discipline / LDS layout; swap the
// compute core 16x16x32 -> 32x32x16 (f16 ubench: 2178 vs 1955 TF, m23/m64 -- +11% per
// FLOP, half the MFMA instructions). Per wave per K-tile: 4mb x 2nb 32x32 blocks x 4 ks
// = 32 MFMA, 4 phases x 8. A/B operand: row = lane&31, k-chunk = ks*2+(lane>>5), read
// chunk XOR (row&7)=(lane&7) -- matches the existing staging swizzle involution; per
// quarter-wave 16 lanes hit 8 chunks x2 = 2-way = free. Any k-permutation error cancels
// (same map on A and B). C/D (m74/m101): col=lane&31, row=(reg&3)+8*(reg>>2)+4*(lane>>5).
//
// Phases per tile (B-nb0 regs live P0->P3, like R6's bLo):
//   P0: read A mb01 (8) + B nb0 (4); stage A(other,h1,To); lgkmcnt(8); MFMA mb01 x nb0
//   P1: read B nb1 (4); MFMA mb01 x nb1
//   P2: read A mb23 (8); stage B(b,h0,Ts); MFMA mb23 x nb1
//   P3: stage B(b,h1,Ts) + A(b,h0,Ts); MFMA mb23 x nb0; vmcnt(6)
// Region safety (re-derived): A.h0 last read P2 -> staged P3-pre (after P2-END);
// A.h1 last read P2 -> staged next-tile P0 (after P3-END); B.h0 last read P1 -> P2-pre;
// B.h1 last read P1 -> P3-pre. vmcnt(6) proof = R6's verbatim (same op order/counts:
// 8 stage-ops per tile, 14 outstanding at P3-end, oldest 8 = the buffer read next).

#define PH_MID() do { \
    __builtin_amdgcn_s_barrier(); \
    asm volatile("s_waitcnt lgkmcnt(0)" ::: "memory"); \
    __builtin_amdgcn_sched_barrier(0); \
    __builtin_amdgcn_s_setprio(1); \
  } while (0)

#define PH_END() do { \
    __builtin_amdgcn_s_setprio(0); \
    __builtin_amdgcn_s_barrier(); \
    __builtin_amdgcn_sched_barrier(0); \
  } while (0)

#define PH_END_VM6() do { \
    __builtin_amdgcn_s_setprio(0); \
    asm volatile("s_waitcnt vmcnt(6)" ::: "memory"); \
    __builtin_amdgcn_s_barrier(); \
    __builtin_amdgcn_sched_barrier(0); \
  } while (0)

__global__ void __launch_bounds__(512, 2) gemm_f16_kernel(
    const short* __restrict__ A,     // [MDIM][KDIM] fp16 bits (xq)
    const short* __restrict__ Bw,    // [NDIM][KDIM] fp16 bits (wq)
    const int* __restrict__ bias,    // [NDIM]
    const float* __restrict__ wscale,// [NDIM]
    const float* __restrict__ p_is,
    const float* __restrict__ p_os,
    int* __restrict__ out) {         // [MDIM][NDIM] int32
    // A bufs: lds[b*16384 + row*64 + ch*8]; B bufs: +32768. 65536 shorts = 128 KiB.
    __shared__ __align__(16) short lds[65536];

    const int tid  = threadIdx.x;
    const int lane = tid & 63;
    const int wave = tid >> 6;
    const int c31  = lane & 31;
    const int h    = lane >> 5;
    const int sw7  = lane & 7;

    // T1: bijective XCD swizzle over the 32x16 grid
    const int flat  = blockIdx.y * gridDim.x + blockIdx.x;
    const int wgid  = (flat & 7) * 64 + (flat >> 3);
    const int m_blk = wgid >> 4;       // 0..31
    const int n_blk = wgid & 15;       // 0..15
    const int m0 = m_blk * 256;
    const int n0 = n_blk * 256;

    const int wmi = wave >> 2;         // 0..1  M wave-row (128 rows each)
    const int wni = wave & 3;          // 0..3  N wave-col (64 cols each)

    // ---- staging (write side): chunk c = l*512 + tid; row=c>>3, kc=c&7;
    //      source column chunk = kc ^ (row&7)  (rows +64 keep row&7 -> per-thread const)
    const int srow = tid >> 3;                       // 0..63
    const int skc  = (tid & 7) ^ (srow & 7);
    const short* gA = A  + (int64_t)(m0 + srow) * KDIM + skc * 8;
    const short* gB = Bw + (int64_t)(n0 + srow) * KDIM + skc * 8;

#define STAGE_A(b, ha, T) do { \
    const short* _g = gA + (int64_t)((ha) * 128) * KDIM + (T) * BK; \
    gload_lds16(_g,             &lds[(b)*16384 + (ha)*8192 + wave*512]); \
    gload_lds16(_g + 64*KDIM,   &lds[(b)*16384 + (ha)*8192 + 4096 + wave*512]); \
  } while (0)
#define STAGE_B(b, ha, T) do { \
    const short* _g = gB + (int64_t)((ha) * 128) * KDIM + (T) * BK; \
    gload_lds16(_g,             &lds[32768 + (b)*16384 + (ha)*8192 + wave*512]); \
    gload_lds16(_g + 64*KDIM,   &lds[32768 + (b)*16384 + (ha)*8192 + 4096 + wave*512]); \
  } while (0)

    // ---- read side (32x32 frags): row = <mult of 32> + c31, row&7 == sw7;
    //      global k-chunk = ks*2 + h, stored at chunk (ks*2+h)^sw7
    const int aRow0 = (wmi * 128 + c31) * 64;           // + mb*2048
    const int bRow0 = 32768 + (wni * 64 + c31) * 64;    // + nb*2048
    int cof[4];
#pragma unroll
    for (int ks = 0; ks < 4; ++ks) cof[ks] = ((ks * 2 + h) ^ sw7) * 8;

#define LDA32(b, mb, ks) (*(const h16x8*)&lds[(b)*16384 + aRow0 + (mb)*2048 + cof[ks]])
#define LDB32(b, nb, ks) (*(const h16x8*)&lds[(b)*16384 + bRow0 + (nb)*2048 + cof[ks]])

    f32x16 acc[4][2];
#pragma unroll
    for (int i = 0; i < 4; ++i)
#pragma unroll
        for (int j = 0; j < 2; ++j) acc[i][j] = (f32x16)0.0f;

    h16x8 aR[2][4], bN0[4], bN1[4];

#define MFMA_PAIR(mbBase, nb, bsrc) do { \
    _Pragma("unroll") for (int ks = 0; ks < 4; ++ks) \
        acc[(mbBase)][nb] = __builtin_amdgcn_mfma_f32_32x32x16_f16( \
            aR[0][ks], bsrc[ks], acc[(mbBase)][nb], 0, 0, 0); \
    _Pragma("unroll") for (int ks = 0; ks < 4; ++ks) \
        acc[(mbBase) + 1][nb] = __builtin_amdgcn_mfma_f32_32x32x16_f16( \
            aR[1][ks], bsrc[ks], acc[(mbBase) + 1][nb], 0, 0, 0); \
  } while (0)

    // one tile in buf b; To = tile going into buf b^1 (A.h1 completion); Ts = tile t+2 -> buf b
#define TILE(b, To, Ts) do { \
    /* P0 */ \
    _Pragma("unroll") for (int ks = 0; ks < 4; ++ks) { \
        aR[0][ks] = LDA32(b, 0, ks); aR[1][ks] = LDA32(b, 1, ks); } \
    _Pragma("unroll") for (int ks = 0; ks < 4; ++ks) bN0[ks] = LDB32(b, 0, ks); \
    STAGE_A((b) ^ 1, 1, To); \
    asm volatile("s_waitcnt lgkmcnt(8)" ::: "memory"); \
    PH_MID(); MFMA_PAIR(0, 0, bN0); PH_END(); \
    /* P1 */ \
    _Pragma("unroll") for (int ks = 0; ks < 4; ++ks) bN1[ks] = LDB32(b, 1, ks); \
    PH_MID(); MFMA_PAIR(0, 1, bN1); PH_END(); \
    /* P2 */ \
    _Pragma("unroll") for (int ks = 0; ks < 4; ++ks) { \
        aR[0][ks] = LDA32(b, 2, ks); aR[1][ks] = LDA32(b, 3, ks); } \
    STAGE_B(b, 0, Ts); \
    asm volatile("s_waitcnt lgkmcnt(8)" ::: "memory"); \
    PH_MID(); MFMA_PAIR(2, 1, bN1); PH_END(); \
    /* P3 */ \
    STAGE_B(b, 1, Ts); \
    STAGE_A(b, 0, Ts); \
    PH_MID(); MFMA_PAIR(2, 0, bN0); PH_END_VM6(); \
  } while (0)

    // ---- prologue: t0 fully (8 ops) + t1 {B.h0, B.h1, A.h0} (6 ops); t1.A.h1 at P0 ----
    STAGE_B(0, 0, 0);  STAGE_B(0, 1, 0);
    STAGE_A(0, 0, 0);  STAGE_A(0, 1, 0);
    STAGE_B(1, 0, 1);  STAGE_B(1, 1, 1);
    STAGE_A(1, 0, 1);
    asm volatile("s_waitcnt vmcnt(6)" ::: "memory");   // t0's 8 (oldest) landed
    __builtin_amdgcn_s_barrier();
    __builtin_amdgcn_sched_barrier(0);

    for (int it = 0; it < NKT / 2; ++it) {
        TILE(0, 2 * it + 1, (2 * it + 2) & (NKT - 1));   // wraps harmlessly at the end
        TILE(1, (2 * it + 2) & (NKT - 1), (2 * it + 3) & (NKT - 1));
    }

    // ---- epilogue: out = round((is*ws[n]*acc + bias[n]) / os) ----
    const float is = p_is[0];
    const float inv_os = 1.0f / p_os[0];
    const int colBase = n0 + wni * 64;

    float alpha[2], beta[2];
#pragma unroll
    for (int nb = 0; nb < 2; ++nb) {
        const int col = colBase + nb * 32 + c31;
        alpha[nb] = is * wscale[col] * inv_os;
        beta[nb]  = (float)bias[col] * inv_os;
    }

    // C/D layout 32x32 (verified m74/m101): col = lane&31, row = (reg&3)+8*(reg>>2)+4*h
#pragma unroll
    for (int mb = 0; mb < 4; ++mb) {
#pragma unroll
        for (int nb = 0; nb < 2; ++nb) {
            const int col = colBase + nb * 32 + c31;
#pragma unroll
            for (int g = 0; g < 4; ++g) {
#pragma unroll
                for (int j = 0; j < 4; ++j) {
                    const int row = m0 + wmi * 128 + mb * 32 + j + g * 8 + h * 4;
                    const float v = acc[mb][nb][g * 4 + j] * alpha[nb] + beta[nb];
                    __builtin_nontemporal_store(__float2int_rn(v),
                                                out + (int64_t)row * NDIM + col);
                }
            }
        }
    }
}

extern "C" void kernel_launch(void* const* d_in, const int* in_sizes, int n_in,
                              void* d_out, int out_size, void* d_ws, size_t ws_size,
                              hipStream_t stream) {
    (void)in_sizes; (void)n_in; (void)out_size; (void)ws_size;
    const float* x      = (const float*)d_in[0];
    const int*   weight = (const int*)d_in[1];
    const int*   bias   = (const int*)d_in[2];
    const float* wscale = (const float*)d_in[3];
    const float* p_is   = (const float*)d_in[4];
    const float* p_os   = (const float*)d_in[5];

    // workspace: xq fp16 [M,K] (64 MiB) + wq fp16 [N,K] (32 MiB) = 96 MiB
    short* xq = (short*)d_ws;
    short* wq = xq + (size_t)MDIM * KDIM;

    quant_kernel<<<3072, 256, 0, stream>>>(x, xq, weight, wq, p_is);

    dim3 grid(NDIM / 256, MDIM / 256);   // 16 x 32 = 512 blocks
    gemm_f16_kernel<<<grid, 512, 0, stream>>>(xq, wq, bias, wscale, p_is, p_os, (int*)d_out);
}